// Round 2
// baseline (1086.968 us; speedup 1.0000x reference)
//
#include <hip/hip_runtime.h>
#include <stdint.h>
#include <math.h>

#pragma clang fp contract(off)

#define N_ROWS 1048576
#define N_CLS  20
#define K_TOP  2000
#define SORT_N 2048

// scalar slots (dwords within scal[])
#define SC_B0   0
#define SC_R1   1
#define SC_T24  4   // final threshold T on (mkey>>8)
#define SC_CNT  5
#define SC_DONE 6

// ws layout
static constexpr size_t OFF_MKEY   = 0;                            // u32[N]
static constexpr size_t OFF_CLS    = OFF_MKEY + 4ull * N_ROWS;     // u8[N]
static constexpr size_t OFF_HIST1  = OFF_CLS + (size_t)N_ROWS;     // u32[256]   -- zeroed region start
static constexpr size_t OFF_HIST16 = OFF_HIST1 + 1024;             // u32[65536]
static constexpr size_t OFF_SCAL   = OFF_HIST16 + 262144;          // u32[16]
static constexpr size_t OFF_GRP    = OFF_SCAL + 64;                // u64[32]    -- zeroed region end
static constexpr size_t OFF_CAND   = OFF_GRP + 256;                // u64[SORT_N]
static constexpr size_t OFF_BNMS   = OFF_CAND + 8ull * SORT_N;     // float4[2048]
static constexpr size_t OFF_MASK   = OFF_BNMS + 16ull * 2048;      // u64[K_TOP*32]
static constexpr int ZERO_DWORDS = (int)((1024 + 262144 + 64 + 256) / 4);  // 65872

__device__ __forceinline__ uint32_t mono_key(float f) {
    uint32_t u = __float_as_uint(f);
    return u ^ ((u & 0x80000000u) ? 0xFFFFFFFFu : 0x80000000u);
}
__device__ __forceinline__ float mono_inv(uint32_t k) {
    uint32_t u = (k & 0x80000000u) ? (k ^ 0x80000000u) : ~k;
    return __uint_as_float(u);
}

// ---- K0: zero the accumulated-scratch region (hist1, hist16, scal, grp)
__global__ __launch_bounds__(256) void k_init(uint32_t* __restrict__ zp) {
    int i = blockIdx.x * 256 + threadIdx.x;
    if (i < ZERO_DWORDS) zp[i] = 0;
}

// ---- K1: per-row max/argmax of logits, store monotone key + class; fused hist over key>>24
__global__ __launch_bounds__(256) void k_score(const float* __restrict__ logits,
                                               uint32_t* __restrict__ mkey,
                                               uint8_t* __restrict__ cls,
                                               uint32_t* __restrict__ hist1) {
    __shared__ uint32_t h[256];
    h[threadIdx.x] = 0;
    __syncthreads();
    int base = blockIdx.x * 1024 + threadIdx.x;
    for (int k = 0; k < 4; ++k) {
        int row = base + k * 256;
        const float4* p = (const float4*)(logits + (size_t)row * N_CLS);
        float v[20];
#pragma unroll
        for (int q = 0; q < 5; ++q) {
            float4 t = p[q];
            v[4 * q + 0] = t.x; v[4 * q + 1] = t.y; v[4 * q + 2] = t.z; v[4 * q + 3] = t.w;
        }
        float m = v[0]; int ci = 0;
#pragma unroll
        for (int c = 1; c < 20; ++c) { if (v[c] > m) { m = v[c]; ci = c; } }
        uint32_t u = mono_key(m);
        mkey[row] = u;
        cls[row] = (uint8_t)ci;
        atomicAdd(&h[u >> 24], 1u);
    }
    __syncthreads();
    uint32_t hv = h[threadIdx.x];
    if (hv) atomicAdd(&hist1[threadIdx.x], hv);
}

// ---- K2: per-block redundant phase-1 find (parallel suffix scan over hist1),
//      then 16-bit restricted histogram (bits 23:8 where top byte == b0)
__global__ __launch_bounds__(256) void k_hist16(const uint32_t* __restrict__ mkey,
                                                const uint32_t* __restrict__ hist1,
                                                uint32_t* __restrict__ hist16,
                                                uint32_t* __restrict__ scal) {
    __shared__ uint32_t sfx[256];
    __shared__ uint32_t sb0, sR1;
    int t = threadIdx.x;
    uint32_t h = hist1[t];
    sfx[t] = h;
    __syncthreads();
    // inclusive suffix sum: sfx[t] = sum_{u>=t} hist1[u]
    for (int off = 1; off < 256; off <<= 1) {
        uint32_t v = (t + off < 256) ? sfx[t + off] : 0;
        __syncthreads();
        sfx[t] += v;
        __syncthreads();
    }
    uint32_t target = (uint32_t)K_TOP;
    if (sfx[t] >= target && (t == 255 || sfx[t + 1] < target)) {
        sb0 = (uint32_t)t;                       // largest bin with cum >= target
        sR1 = target - (sfx[t] - h);             // remaining rank within bin b0
    }
    __syncthreads();
    uint32_t b0 = sb0;
    int base = blockIdx.x * 1024 + t;
    for (int k = 0; k < 4; ++k) {
        uint32_t u = mkey[base + k * 256];
        if ((u >> 24) == b0) atomicAdd(&hist16[(u >> 8) & 0xFFFFu], 1u);
    }
    if (blockIdx.x == 0 && t == 0) { scal[SC_B0] = b0; scal[SC_R1] = sR1; }
}

// ---- K3: parallel find over 65536 bins -> final 24-bit threshold (minus 1-bin safety)
__global__ __launch_bounds__(1024) void k_find16(const uint32_t* __restrict__ hist16,
                                                 uint32_t* __restrict__ scal) {
    __shared__ uint32_t cs[1024];
    __shared__ uint32_t binbuf[64];
    __shared__ int schunk;
    int t = threadIdx.x;
    uint32_t s = 0;
    const uint4* p = (const uint4*)(hist16 + (size_t)t * 64);
#pragma unroll
    for (int i = 0; i < 16; ++i) { uint4 v = p[i]; s += v.x + v.y + v.z + v.w; }
    cs[t] = s;
    __syncthreads();
    for (int off = 1; off < 1024; off <<= 1) {
        uint32_t v = (t + off < 1024) ? cs[t + off] : 0;
        __syncthreads();
        cs[t] += v;
        __syncthreads();
    }
    uint32_t R1 = scal[SC_R1];
    if (cs[t] >= R1 && (t == 1023 || cs[t + 1] < R1)) schunk = t;
    __syncthreads();
    int c = schunk;
    uint32_t above_chunks = (c == 1023) ? 0u : cs[c + 1];
    if (t < 64) binbuf[t] = hist16[(size_t)c * 64 + t];
    __syncthreads();
    if (t == 0) {
        uint32_t cum = above_chunks;
        int b = 63;
        for (; b >= 0; --b) { cum += binbuf[b]; if (cum >= R1) break; }
        if (b < 0) b = 0;
        uint32_t t24 = (scal[SC_B0] << 16) | (uint32_t)(c * 64 + b);
        scal[SC_T24] = (t24 > 0) ? (t24 - 1) : 0;   // -1 bin safety: covers rounded-score ties
    }
}

// ---- K4: compact candidates (mkey>>8 >= T)
__global__ __launch_bounds__(256) void k_compact(const uint32_t* __restrict__ mkey,
                                                 uint32_t* __restrict__ scal,
                                                 uint64_t* __restrict__ cand) {
    uint32_t T = scal[SC_T24];
    int base = blockIdx.x * 1024 + threadIdx.x;
    for (int k = 0; k < 4; ++k) {
        int row = base + k * 256;
        uint32_t u = mkey[row];
        if ((u >> 8) >= T) {
            uint32_t pos = atomicAdd(&scal[SC_CNT], 1u);
            if (pos < (uint32_t)SORT_N) cand[pos] = ((uint64_t)u << 32) | (uint32_t)row;
        }
    }
}

// ---- K5: single-block: sigmoid, bitonic sort by (score desc, idx asc),
//      decode boxes, write outputs, reduce max_coord, build offset boxes for NMS
__global__ __launch_bounds__(1024) void k_sort(const uint64_t* __restrict__ cand,
                                               const uint32_t* __restrict__ scal,
                                               const float* __restrict__ deltas,
                                               const float* __restrict__ locs,
                                               const int* __restrict__ stridep,
                                               const uint8_t* __restrict__ cls,
                                               float* __restrict__ out,
                                               float4* __restrict__ bnms) {
    __shared__ uint64_t keys[SORT_N];
    __shared__ float boxes[K_TOP * 4];
    __shared__ uint8_t ucls[K_TOP];
    __shared__ float red[16];
    int tid = threadIdx.x;
    uint32_t M = scal[SC_CNT];
    if (M > (uint32_t)SORT_N) M = SORT_N;

    for (int t = tid; t < SORT_N; t += 1024) {
        if (t < (int)M) {
            uint64_t cd = cand[t];
            uint32_t mk = (uint32_t)(cd >> 32);
            uint32_t idx = (uint32_t)cd;
            float m = mono_inv(mk);
            float ef = (float)exp(-(double)m);        // ~correctly-rounded fp32 expf
            float s = 1.0f / (1.0f + ef);
            keys[t] = ((uint64_t)(~__float_as_uint(s)) << 32) | idx;
        } else {
            keys[t] = ~0ull;
        }
    }
    __syncthreads();
    for (int k = 2; k <= SORT_N; k <<= 1) {
        for (int j = k >> 1; j > 0; j >>= 1) {
            for (int t = tid; t < SORT_N; t += 1024) {
                int ixj = t ^ j;
                if (ixj > t) {
                    uint64_t a = keys[t], b = keys[ixj];
                    bool up = ((t & k) == 0);
                    if ((a > b) == up) { keys[t] = b; keys[ixj] = a; }
                }
            }
            __syncthreads();
        }
    }

    float stridef = (float)(*stridep);
    for (int r = tid; r < K_TOP; r += 1024) {
        uint64_t key = keys[r];
        uint32_t idx = (uint32_t)(key & 0xFFFFFFFFull);
        idx &= (N_ROWS - 1);                          // OOB safety
        uint32_t sbits = ~(uint32_t)(key >> 32);
        float s = __uint_as_float(sbits);
        float4 dl = ((const float4*)deltas)[idx];
        float2 lc = ((const float2*)locs)[idx];
        float d0 = dl.x * stridef, d1 = dl.y * stridef, d2 = dl.z * stridef, d3 = dl.w * stridef;
        float b0 = lc.x - d0, b1 = lc.y - d1, b2 = lc.x + d2, b3 = lc.y + d3;
        out[4 * r + 0] = b0; out[4 * r + 1] = b1; out[4 * r + 2] = b2; out[4 * r + 3] = b3;
        out[8000 + r] = s;
        uint8_t c = cls[idx];
        out[10000 + r] = (float)c;
        boxes[4 * r + 0] = b0; boxes[4 * r + 1] = b1; boxes[4 * r + 2] = b2; boxes[4 * r + 3] = b3;
        ucls[r] = c;
    }
    __syncthreads();
    float mx = -3.4e38f;
    for (int t = tid; t < K_TOP * 4; t += 1024) mx = fmaxf(mx, boxes[t]);
    for (int o = 32; o > 0; o >>= 1) mx = fmaxf(mx, __shfl_down(mx, o));
    if ((tid & 63) == 0) red[tid >> 6] = mx;
    __syncthreads();
    if (tid == 0) {
        float m2 = red[0];
        for (int i = 1; i < 16; ++i) m2 = fmaxf(m2, red[i]);
        red[0] = m2 + 1.0f;                           // max_coord + 1
    }
    __syncthreads();
    float off1 = red[0];
    for (int r = tid; r < K_TOP; r += 1024) {
        float o = (float)ucls[r] * off1;
        float4 b;
        b.x = boxes[4 * r + 0] + o;
        b.y = boxes[4 * r + 1] + o;
        b.z = boxes[4 * r + 2] + o;
        b.w = boxes[4 * r + 3] + o;
        bnms[r] = b;
    }
}

// ---- K6: pairwise suppression mask (quirky IoU replicated exactly),
//      fused sequential NMS scan in the last-finishing block
__global__ __launch_bounds__(256) void k_mask(const float4* __restrict__ bnms,
                                              uint64_t* __restrict__ mask,
                                              unsigned long long* __restrict__ grp,
                                              uint32_t* __restrict__ scal,
                                              float* __restrict__ out) {
    int wave = (int)((blockIdx.x * 256 + threadIdx.x) >> 6);
    int lane = threadIdx.x & 63;
    int i = wave >> 5;
    int jb = wave & 31;
    int j = jb * 64 + lane;
    float4 bi = bnms[i];
    bool sup = false;
    if (j < K_TOP && j > i) {
        float4 bj = bnms[j];
        float x1i = bi.x, y1i = bi.w, x2i = bi.z, y2i = bi.y;
        float x1j = bj.x, y1j = bj.w, x2j = bj.z, y2j = bj.y;
        float ai = (x2i - x1i) * (y2i - y1i);
        float aj = (x2j - x1j) * (y2j - y1j);
        float xx1 = fmaxf(x1i, x1j);
        float yy1 = fminf(y1i, y1j);
        float xx2 = fminf(x2i, x2j);
        float yy2 = fmaxf(y2i, y2j);
        float inter = fabsf(xx2 - xx1) * fabsf(yy2 - yy1);
        float iou = inter / ((ai + aj) - inter);
        sup = iou > 0.5f;
    }
    unsigned long long bits = __ballot(sup);
    if (lane == 0) {
        mask[(size_t)i * 32 + jb] = bits;
        if (bits) atomicOr(&grp[i >> 6], 1ull << (i & 63));
    }

    // last-block-done: the final block performs the sequential scan
    __shared__ int lastdone;
    __threadfence();
    __syncthreads();
    if (threadIdx.x == 0) {
        unsigned old = atomicAdd(&scal[SC_DONE], 1u);
        lastdone = (old == (unsigned)(gridDim.x - 1)) ? 1 : 0;
    }
    __syncthreads();
    if (!lastdone) return;
    __threadfence();  // acquire: see all blocks' mask/grp writes

    if (threadIdx.x < 64) {
        int l = threadIdx.x;  // lane w<32 holds active word w
        uint64_t active = ~0ull;
        for (int g = 0; g < 32; ++g) {
            unsigned long long nz = grp[g];
            while (nz) {
                int b = __ffsll((long long)nz) - 1;
                nz &= nz - 1;
                int ii = g * 64 + b;
                uint64_t aw = __shfl(active, g);
                bool kept = (aw >> b) & 1ull;
                uint64_t m = (l < 32) ? mask[(size_t)ii * 32 + l] : 0ull;
                if (kept) active &= ~m;
            }
        }
        if (l < 32) {
            for (int b = 0; b < 64; ++b) {
                int jj = l * 64 + b;
                if (jj < K_TOP) out[12000 + jj] = ((active >> b) & 1ull) ? 1.0f : 0.0f;
            }
        }
    }
}

extern "C" void kernel_launch(void* const* d_in, const int* in_sizes, int n_in,
                              void* d_out, int out_size, void* d_ws, size_t ws_size,
                              hipStream_t stream) {
    const float* deltas = (const float*)d_in[0];
    const float* locs   = (const float*)d_in[1];
    const float* logits = (const float*)d_in[2];
    const int*   stridep = (const int*)d_in[3];
    float* out = (float*)d_out;
    char* ws = (char*)d_ws;

    uint32_t* mkey   = (uint32_t*)(ws + OFF_MKEY);
    uint8_t*  cls    = (uint8_t*)(ws + OFF_CLS);
    uint32_t* hist1  = (uint32_t*)(ws + OFF_HIST1);
    uint32_t* hist16 = (uint32_t*)(ws + OFF_HIST16);
    uint32_t* scal   = (uint32_t*)(ws + OFF_SCAL);
    unsigned long long* grp = (unsigned long long*)(ws + OFF_GRP);
    uint64_t* cand   = (uint64_t*)(ws + OFF_CAND);
    float4*   bnms   = (float4*)(ws + OFF_BNMS);
    uint64_t* mask   = (uint64_t*)(ws + OFF_MASK);

    k_init<<<dim3((ZERO_DWORDS + 255) / 256), dim3(256), 0, stream>>>(hist1);
    k_score<<<dim3(1024), dim3(256), 0, stream>>>(logits, mkey, cls, hist1);
    k_hist16<<<dim3(1024), dim3(256), 0, stream>>>(mkey, hist1, hist16, scal);
    k_find16<<<dim3(1), dim3(1024), 0, stream>>>(hist16, scal);
    k_compact<<<dim3(1024), dim3(256), 0, stream>>>(mkey, scal, cand);
    k_sort<<<dim3(1), dim3(1024), 0, stream>>>(cand, scal, deltas, locs, stridep, cls, out, bnms);
    k_mask<<<dim3((K_TOP * 32) / 4), dim3(256), 0, stream>>>(bnms, mask, grp, scal, out);
}

// Round 3
// 145.744 us; speedup vs baseline: 7.4581x; 7.4581x over previous
//
#include <hip/hip_runtime.h>
#include <stdint.h>
#include <math.h>

#pragma clang fp contract(off)

#define N_ROWS 1048576
#define N_CLS  20
#define K_TOP  2000
#define SORT_N 2048

// scalar slots (dwords within scal[])
#define SC_B0   0
#define SC_R1   1
#define SC_T24  4   // final threshold T on (mkey>>8)
#define SC_CNT  5

// ws layout
static constexpr size_t OFF_MKEY   = 0;                            // u32[N]
static constexpr size_t OFF_CLS    = OFF_MKEY + 4ull * N_ROWS;     // u8[N]
static constexpr size_t OFF_HIST1  = OFF_CLS + (size_t)N_ROWS;     // u32[256]   -- zeroed region start
static constexpr size_t OFF_HIST16 = OFF_HIST1 + 1024;             // u32[65536]
static constexpr size_t OFF_SCAL   = OFF_HIST16 + 262144;          // u32[16]
static constexpr size_t OFF_GRP    = OFF_SCAL + 64;                // u64[32]    -- zeroed region end
static constexpr size_t OFF_CAND   = OFF_GRP + 256;                // u64[SORT_N]
static constexpr size_t OFF_BNMS   = OFF_CAND + 8ull * SORT_N;     // float4[2048]
static constexpr size_t OFF_MASK   = OFF_BNMS + 16ull * 2048;      // u64[K_TOP*32]
static constexpr int ZERO_DWORDS = (int)((1024 + 262144 + 64 + 256) / 4);  // 65872

__device__ __forceinline__ uint32_t mono_key(float f) {
    uint32_t u = __float_as_uint(f);
    return u ^ ((u & 0x80000000u) ? 0xFFFFFFFFu : 0x80000000u);
}
__device__ __forceinline__ float mono_inv(uint32_t k) {
    uint32_t u = (k & 0x80000000u) ? (k ^ 0x80000000u) : ~k;
    return __uint_as_float(u);
}

// ---- K0: zero the accumulated-scratch region (hist1, hist16, scal, grp)
__global__ __launch_bounds__(256) void k_init(uint32_t* __restrict__ zp) {
    int i = blockIdx.x * 256 + threadIdx.x;
    if (i < ZERO_DWORDS) zp[i] = 0;
}

// ---- K1: per-row max/argmax of logits, store monotone key + class; fused hist over key>>24
__global__ __launch_bounds__(256) void k_score(const float* __restrict__ logits,
                                               uint32_t* __restrict__ mkey,
                                               uint8_t* __restrict__ cls,
                                               uint32_t* __restrict__ hist1) {
    __shared__ uint32_t h[256];
    h[threadIdx.x] = 0;
    __syncthreads();
    int base = blockIdx.x * 1024 + threadIdx.x;
    for (int k = 0; k < 4; ++k) {
        int row = base + k * 256;
        const float4* p = (const float4*)(logits + (size_t)row * N_CLS);
        float v[20];
#pragma unroll
        for (int q = 0; q < 5; ++q) {
            float4 t = p[q];
            v[4 * q + 0] = t.x; v[4 * q + 1] = t.y; v[4 * q + 2] = t.z; v[4 * q + 3] = t.w;
        }
        float m = v[0]; int ci = 0;
#pragma unroll
        for (int c = 1; c < 20; ++c) { if (v[c] > m) { m = v[c]; ci = c; } }
        uint32_t u = mono_key(m);
        mkey[row] = u;
        cls[row] = (uint8_t)ci;
        atomicAdd(&h[u >> 24], 1u);
    }
    __syncthreads();
    uint32_t hv = h[threadIdx.x];
    if (hv) atomicAdd(&hist1[threadIdx.x], hv);
}

// ---- K2: per-block redundant phase-1 find (parallel suffix scan over hist1),
//      then 16-bit restricted histogram (bits 23:8 where top byte == b0)
__global__ __launch_bounds__(256) void k_hist16(const uint32_t* __restrict__ mkey,
                                                const uint32_t* __restrict__ hist1,
                                                uint32_t* __restrict__ hist16,
                                                uint32_t* __restrict__ scal) {
    __shared__ uint32_t sfx[256];
    __shared__ uint32_t sb0, sR1;
    int t = threadIdx.x;
    uint32_t h = hist1[t];
    sfx[t] = h;
    __syncthreads();
    // inclusive suffix sum: sfx[t] = sum_{u>=t} hist1[u]
    for (int off = 1; off < 256; off <<= 1) {
        uint32_t v = (t + off < 256) ? sfx[t + off] : 0;
        __syncthreads();
        sfx[t] += v;
        __syncthreads();
    }
    uint32_t target = (uint32_t)K_TOP;
    if (sfx[t] >= target && (t == 255 || sfx[t + 1] < target)) {
        sb0 = (uint32_t)t;                       // largest bin with cum >= target
        sR1 = target - (sfx[t] - h);             // remaining rank within bin b0
    }
    __syncthreads();
    uint32_t b0 = sb0;
    int base = blockIdx.x * 1024 + t;
    for (int k = 0; k < 4; ++k) {
        uint32_t u = mkey[base + k * 256];
        if ((u >> 24) == b0) atomicAdd(&hist16[(u >> 8) & 0xFFFFu], 1u);
    }
    if (blockIdx.x == 0 && t == 0) { scal[SC_B0] = b0; scal[SC_R1] = sR1; }
}

// ---- K3: parallel find over 65536 bins -> final 24-bit threshold (minus 1-bin safety)
__global__ __launch_bounds__(1024) void k_find16(const uint32_t* __restrict__ hist16,
                                                 uint32_t* __restrict__ scal) {
    __shared__ uint32_t cs[1024];
    __shared__ uint32_t binbuf[64];
    __shared__ int schunk;
    int t = threadIdx.x;
    uint32_t s = 0;
    const uint4* p = (const uint4*)(hist16 + (size_t)t * 64);
#pragma unroll
    for (int i = 0; i < 16; ++i) { uint4 v = p[i]; s += v.x + v.y + v.z + v.w; }
    cs[t] = s;
    __syncthreads();
    for (int off = 1; off < 1024; off <<= 1) {
        uint32_t v = (t + off < 1024) ? cs[t + off] : 0;
        __syncthreads();
        cs[t] += v;
        __syncthreads();
    }
    uint32_t R1 = scal[SC_R1];
    if (cs[t] >= R1 && (t == 1023 || cs[t + 1] < R1)) schunk = t;
    __syncthreads();
    int c = schunk;
    uint32_t above_chunks = (c == 1023) ? 0u : cs[c + 1];
    if (t < 64) binbuf[t] = hist16[(size_t)c * 64 + t];
    __syncthreads();
    if (t == 0) {
        uint32_t cum = above_chunks;
        int b = 63;
        for (; b >= 0; --b) { cum += binbuf[b]; if (cum >= R1) break; }
        if (b < 0) b = 0;
        uint32_t t24 = (scal[SC_B0] << 16) | (uint32_t)(c * 64 + b);
        scal[SC_T24] = (t24 > 0) ? (t24 - 1) : 0;   // -1 bin safety: covers rounded-score ties
    }
}

// ---- K4: compact candidates (mkey>>8 >= T)
__global__ __launch_bounds__(256) void k_compact(const uint32_t* __restrict__ mkey,
                                                 uint32_t* __restrict__ scal,
                                                 uint64_t* __restrict__ cand) {
    uint32_t T = scal[SC_T24];
    int base = blockIdx.x * 1024 + threadIdx.x;
    for (int k = 0; k < 4; ++k) {
        int row = base + k * 256;
        uint32_t u = mkey[row];
        if ((u >> 8) >= T) {
            uint32_t pos = atomicAdd(&scal[SC_CNT], 1u);
            if (pos < (uint32_t)SORT_N) cand[pos] = ((uint64_t)u << 32) | (uint32_t)row;
        }
    }
}

// ---- K5: single-block: sigmoid, bitonic sort by (score desc, idx asc),
//      decode boxes, write outputs, reduce max_coord, build offset boxes for NMS
__global__ __launch_bounds__(1024) void k_sort(const uint64_t* __restrict__ cand,
                                               const uint32_t* __restrict__ scal,
                                               const float* __restrict__ deltas,
                                               const float* __restrict__ locs,
                                               const int* __restrict__ stridep,
                                               const uint8_t* __restrict__ cls,
                                               float* __restrict__ out,
                                               float4* __restrict__ bnms) {
    __shared__ uint64_t keys[SORT_N];
    __shared__ float boxes[K_TOP * 4];
    __shared__ uint8_t ucls[K_TOP];
    __shared__ float red[16];
    int tid = threadIdx.x;
    uint32_t M = scal[SC_CNT];
    if (M > (uint32_t)SORT_N) M = SORT_N;

    for (int t = tid; t < SORT_N; t += 1024) {
        if (t < (int)M) {
            uint64_t cd = cand[t];
            uint32_t mk = (uint32_t)(cd >> 32);
            uint32_t idx = (uint32_t)cd;
            float m = mono_inv(mk);
            float ef = (float)exp(-(double)m);        // ~correctly-rounded fp32 expf
            float s = 1.0f / (1.0f + ef);
            keys[t] = ((uint64_t)(~__float_as_uint(s)) << 32) | idx;
        } else {
            keys[t] = ~0ull;
        }
    }
    __syncthreads();
    for (int k = 2; k <= SORT_N; k <<= 1) {
        for (int j = k >> 1; j > 0; j >>= 1) {
            for (int t = tid; t < SORT_N; t += 1024) {
                int ixj = t ^ j;
                if (ixj > t) {
                    uint64_t a = keys[t], b = keys[ixj];
                    bool up = ((t & k) == 0);
                    if ((a > b) == up) { keys[t] = b; keys[ixj] = a; }
                }
            }
            __syncthreads();
        }
    }

    float stridef = (float)(*stridep);
    for (int r = tid; r < K_TOP; r += 1024) {
        uint64_t key = keys[r];
        uint32_t idx = (uint32_t)(key & 0xFFFFFFFFull);
        idx &= (N_ROWS - 1);                          // OOB safety
        uint32_t sbits = ~(uint32_t)(key >> 32);
        float s = __uint_as_float(sbits);
        float4 dl = ((const float4*)deltas)[idx];
        float2 lc = ((const float2*)locs)[idx];
        float d0 = dl.x * stridef, d1 = dl.y * stridef, d2 = dl.z * stridef, d3 = dl.w * stridef;
        float b0 = lc.x - d0, b1 = lc.y - d1, b2 = lc.x + d2, b3 = lc.y + d3;
        out[4 * r + 0] = b0; out[4 * r + 1] = b1; out[4 * r + 2] = b2; out[4 * r + 3] = b3;
        out[8000 + r] = s;
        uint8_t c = cls[idx];
        out[10000 + r] = (float)c;
        boxes[4 * r + 0] = b0; boxes[4 * r + 1] = b1; boxes[4 * r + 2] = b2; boxes[4 * r + 3] = b3;
        ucls[r] = c;
    }
    __syncthreads();
    float mx = -3.4e38f;
    for (int t = tid; t < K_TOP * 4; t += 1024) mx = fmaxf(mx, boxes[t]);
    for (int o = 32; o > 0; o >>= 1) mx = fmaxf(mx, __shfl_down(mx, o));
    if ((tid & 63) == 0) red[tid >> 6] = mx;
    __syncthreads();
    if (tid == 0) {
        float m2 = red[0];
        for (int i = 1; i < 16; ++i) m2 = fmaxf(m2, red[i]);
        red[0] = m2 + 1.0f;                           // max_coord + 1
    }
    __syncthreads();
    float off1 = red[0];
    for (int r = tid; r < K_TOP; r += 1024) {
        float o = (float)ucls[r] * off1;
        float4 b;
        b.x = boxes[4 * r + 0] + o;
        b.y = boxes[4 * r + 1] + o;
        b.z = boxes[4 * r + 2] + o;
        b.w = boxes[4 * r + 3] + o;
        bnms[r] = b;
    }
}

// ---- K6: pairwise suppression mask (quirky IoU replicated exactly). NO fences here:
//      the kernel boundary before k_scan is the (cheap, one-time) coherence point.
__global__ __launch_bounds__(256) void k_mask(const float4* __restrict__ bnms,
                                              uint64_t* __restrict__ mask,
                                              unsigned long long* __restrict__ grp) {
    int wave = (int)((blockIdx.x * 256 + threadIdx.x) >> 6);
    int lane = threadIdx.x & 63;
    int i = wave >> 5;
    int jb = wave & 31;
    int j = jb * 64 + lane;
    float4 bi = bnms[i];
    bool sup = false;
    if (j < K_TOP && j > i) {
        float4 bj = bnms[j];
        float x1i = bi.x, y1i = bi.w, x2i = bi.z, y2i = bi.y;
        float x1j = bj.x, y1j = bj.w, x2j = bj.z, y2j = bj.y;
        float ai = (x2i - x1i) * (y2i - y1i);
        float aj = (x2j - x1j) * (y2j - y1j);
        float xx1 = fmaxf(x1i, x1j);
        float yy1 = fminf(y1i, y1j);
        float xx2 = fminf(x2i, x2j);
        float yy2 = fmaxf(y2i, y2j);
        float inter = fabsf(xx2 - xx1) * fabsf(yy2 - yy1);
        float iou = inter / ((ai + aj) - inter);
        sup = iou > 0.5f;
    }
    unsigned long long bits = __ballot(sup);
    if (lane == 0) {
        mask[(size_t)i * 32 + jb] = bits;
        if (bits) atomicOr(&grp[i >> 6], 1ull << (i & 63));
    }
}

// ---- K7: sequential NMS scan over nonzero-mask rows only; final active == keep
__global__ void k_scan(const uint64_t* __restrict__ mask,
                       const unsigned long long* __restrict__ grp,
                       float* __restrict__ out) {
    int lane = threadIdx.x;  // 64 threads, lane w<32 holds active word w
    uint64_t active = ~0ull;
    for (int g = 0; g < 32; ++g) {
        unsigned long long nz = grp[g];
        while (nz) {
            int b = __ffsll((long long)nz) - 1;
            nz &= nz - 1;
            int i = g * 64 + b;
            uint64_t aw = __shfl(active, g);
            bool kept = (aw >> b) & 1ull;
            uint64_t m = (lane < 32) ? mask[(size_t)i * 32 + lane] : 0ull;
            if (kept) active &= ~m;
        }
    }
    if (lane < 32) {
        for (int b = 0; b < 64; ++b) {
            int j = lane * 64 + b;
            if (j < K_TOP) out[12000 + j] = ((active >> b) & 1ull) ? 1.0f : 0.0f;
        }
    }
}

extern "C" void kernel_launch(void* const* d_in, const int* in_sizes, int n_in,
                              void* d_out, int out_size, void* d_ws, size_t ws_size,
                              hipStream_t stream) {
    const float* deltas = (const float*)d_in[0];
    const float* locs   = (const float*)d_in[1];
    const float* logits = (const float*)d_in[2];
    const int*   stridep = (const int*)d_in[3];
    float* out = (float*)d_out;
    char* ws = (char*)d_ws;

    uint32_t* mkey   = (uint32_t*)(ws + OFF_MKEY);
    uint8_t*  cls    = (uint8_t*)(ws + OFF_CLS);
    uint32_t* hist1  = (uint32_t*)(ws + OFF_HIST1);
    uint32_t* hist16 = (uint32_t*)(ws + OFF_HIST16);
    uint32_t* scal   = (uint32_t*)(ws + OFF_SCAL);
    unsigned long long* grp = (unsigned long long*)(ws + OFF_GRP);
    uint64_t* cand   = (uint64_t*)(ws + OFF_CAND);
    float4*   bnms   = (float4*)(ws + OFF_BNMS);
    uint64_t* mask   = (uint64_t*)(ws + OFF_MASK);

    k_init<<<dim3((ZERO_DWORDS + 255) / 256), dim3(256), 0, stream>>>(hist1);
    k_score<<<dim3(1024), dim3(256), 0, stream>>>(logits, mkey, cls, hist1);
    k_hist16<<<dim3(1024), dim3(256), 0, stream>>>(mkey, hist1, hist16, scal);
    k_find16<<<dim3(1), dim3(1024), 0, stream>>>(hist16, scal);
    k_compact<<<dim3(1024), dim3(256), 0, stream>>>(mkey, scal, cand);
    k_sort<<<dim3(1), dim3(1024), 0, stream>>>(cand, scal, deltas, locs, stridep, cls, out, bnms);
    k_mask<<<dim3((K_TOP * 32) / 4), dim3(256), 0, stream>>>(bnms, mask, grp);
    k_scan<<<dim3(1), dim3(64), 0, stream>>>(mask, grp, out);
}

// Round 4
// 121.778 us; speedup vs baseline: 8.9258x; 1.1968x over previous
//
#include <hip/hip_runtime.h>
#include <stdint.h>
#include <math.h>

#pragma clang fp contract(off)

#define N_ROWS 1048576
#define N_CLS  20
#define K_TOP  2000
#define CAND_MAX 4096
#define H1_COPIES 16

// scalar slots (dwords within scal[])
#define SC_B0   0
#define SC_R1   1
#define SC_T24  4   // final threshold T on (mkey>>8)
#define SC_CNT  5
#define SC_MAXK 7   // mono-key of max box coord over the 2000 selected

// ws layout
static constexpr size_t OFF_MKEY   = 0;                              // u32[N]
static constexpr size_t OFF_CLS    = OFF_MKEY + 4ull * N_ROWS;       // u8[N]
static constexpr size_t OFF_HIST1  = OFF_CLS + (size_t)N_ROWS;       // u32[16*256] -- zeroed by k_init
static constexpr size_t OFF_SCAL   = OFF_HIST1 + 4ull * H1_COPIES * 256;  // u32[16]
static constexpr size_t OFF_GRP    = OFF_SCAL + 64;                  // u64[32]
static constexpr size_t OFF_HIST16 = OFF_GRP + 256;                  // u32[65536] -- zeroed by k_score
static constexpr size_t OFF_CAND   = OFF_HIST16 + 262144;            // u64[CAND_MAX]
static constexpr size_t OFF_MASK   = OFF_CAND + 8ull * CAND_MAX;     // u64[K_TOP*32]
static constexpr int ZERO_DWORDS = H1_COPIES * 256 + 16 + 64;        // hist1 + scal + grp = 4176

__device__ __forceinline__ uint32_t mono_key(float f) {
    uint32_t u = __float_as_uint(f);
    return u ^ ((u & 0x80000000u) ? 0xFFFFFFFFu : 0x80000000u);
}
__device__ __forceinline__ float mono_inv(uint32_t k) {
    uint32_t u = (k & 0x80000000u) ? (k ^ 0x80000000u) : ~k;
    return __uint_as_float(u);
}

// ---- K0: zero hist1 copies + scal + grp (single small block)
__global__ __launch_bounds__(1024) void k_init(uint32_t* __restrict__ zp) {
    for (int i = threadIdx.x; i < ZERO_DWORDS; i += 1024) zp[i] = 0;
}

// ---- K1: per-row max/argmax of logits via coalesced LDS staging.
//      Also zeroes this block's hist16 chunk and accumulates a 16-way-spread hist1.
__global__ __launch_bounds__(256) void k_score(const float* __restrict__ logits,
                                               uint32_t* __restrict__ mkey,
                                               uint8_t* __restrict__ cls,
                                               uint32_t* __restrict__ hist1,
                                               uint32_t* __restrict__ hist16) {
    __shared__ uint32_t stage[256 * 21];   // 256 rows x 20 words, padded to 21 (2-way banks = free)
    __shared__ uint32_t h[256];
    int t = threadIdx.x;
    h[t] = 0;
    if (t < 64) hist16[blockIdx.x * 64 + t] = 0;   // consumed only by later kernels
    // precompute the 20 LDS word-addresses this thread's 5 float4 loads scatter to
    int waddr[20];
#pragma unroll
    for (int q = 0; q < 5; ++q) {
#pragma unroll
        for (int e = 0; e < 4; ++e) {
            int w = (q * 256 + t) * 4 + e;
            int r = w / 20, c = w - r * 20;
            waddr[q * 4 + e] = r * 21 + c;
        }
    }
    __syncthreads();
    size_t blockRowBase = (size_t)blockIdx.x * 1024;
    for (int g = 0; g < 4; ++g) {
        const float4* src = (const float4*)(logits + (blockRowBase + (size_t)g * 256) * N_CLS);
#pragma unroll
        for (int q = 0; q < 5; ++q) {
            float4 v = src[q * 256 + t];            // fully coalesced 16B/lane
            stage[waddr[q * 4 + 0]] = __float_as_uint(v.x);
            stage[waddr[q * 4 + 1]] = __float_as_uint(v.y);
            stage[waddr[q * 4 + 2]] = __float_as_uint(v.z);
            stage[waddr[q * 4 + 3]] = __float_as_uint(v.w);
        }
        __syncthreads();
        const uint32_t* row = &stage[t * 21];
        float m = __uint_as_float(row[0]); int ci = 0;
#pragma unroll
        for (int c = 1; c < 20; ++c) {
            float v = __uint_as_float(row[c]);
            if (v > m) { m = v; ci = c; }
        }
        size_t rowIdx = blockRowBase + (size_t)g * 256 + t;
        uint32_t u = mono_key(m);
        mkey[rowIdx] = u;
        cls[rowIdx] = (uint8_t)ci;
        atomicAdd(&h[u >> 24], 1u);
        __syncthreads();                            // before next group overwrites stage
    }
    uint32_t hv = h[t];
    if (hv) atomicAdd(&hist1[(blockIdx.x & (H1_COPIES - 1)) * 256 + t], hv);
}

// ---- K2: per-block redundant phase-1 find (suffix scan over summed hist1 copies),
//      then 16-bit restricted histogram (bits 23:8 where top byte == b0)
__global__ __launch_bounds__(256) void k_hist16(const uint32_t* __restrict__ mkey,
                                                const uint32_t* __restrict__ hist1,
                                                uint32_t* __restrict__ hist16,
                                                uint32_t* __restrict__ scal) {
    __shared__ uint32_t sfx[256];
    __shared__ uint32_t sb0, sR1;
    int t = threadIdx.x;
    uint32_t h = 0;
#pragma unroll
    for (int k = 0; k < H1_COPIES; ++k) h += hist1[k * 256 + t];
    sfx[t] = h;
    __syncthreads();
    for (int off = 1; off < 256; off <<= 1) {
        uint32_t v = (t + off < 256) ? sfx[t + off] : 0;
        __syncthreads();
        sfx[t] += v;
        __syncthreads();
    }
    uint32_t target = (uint32_t)K_TOP;
    if (sfx[t] >= target && (t == 255 || sfx[t + 1] < target)) {
        sb0 = (uint32_t)t;
        sR1 = target - (sfx[t] - h);
    }
    __syncthreads();
    uint32_t b0 = sb0;
    int base = blockIdx.x * 1024 + t;
    for (int k = 0; k < 4; ++k) {
        uint32_t u = mkey[base + k * 256];
        if ((u >> 24) == b0) atomicAdd(&hist16[(u >> 8) & 0xFFFFu], 1u);
    }
    if (blockIdx.x == 0 && t == 0) { scal[SC_B0] = b0; scal[SC_R1] = sR1; }
}

// ---- K3: parallel find over 65536 bins -> final 24-bit threshold (minus 1-bin safety)
__global__ __launch_bounds__(1024) void k_find16(const uint32_t* __restrict__ hist16,
                                                 uint32_t* __restrict__ scal) {
    __shared__ uint32_t cs[1024];
    __shared__ uint32_t binbuf[64];
    __shared__ int schunk;
    int t = threadIdx.x;
    uint32_t s = 0;
    const uint4* p = (const uint4*)(hist16 + (size_t)t * 64);
#pragma unroll
    for (int i = 0; i < 16; ++i) { uint4 v = p[i]; s += v.x + v.y + v.z + v.w; }
    cs[t] = s;
    __syncthreads();
    for (int off = 1; off < 1024; off <<= 1) {
        uint32_t v = (t + off < 1024) ? cs[t + off] : 0;
        __syncthreads();
        cs[t] += v;
        __syncthreads();
    }
    uint32_t R1 = scal[SC_R1];
    if (cs[t] >= R1 && (t == 1023 || cs[t + 1] < R1)) schunk = t;
    __syncthreads();
    int c = schunk;
    uint32_t above_chunks = (c == 1023) ? 0u : cs[c + 1];
    if (t < 64) binbuf[t] = hist16[(size_t)c * 64 + t];
    __syncthreads();
    if (t == 0) {
        uint32_t cum = above_chunks;
        int b = 63;
        for (; b >= 0; --b) { cum += binbuf[b]; if (cum >= R1) break; }
        if (b < 0) b = 0;
        uint32_t t24 = (scal[SC_B0] << 16) | (uint32_t)(c * 64 + b);
        scal[SC_T24] = (t24 > 0) ? (t24 - 1) : 0;   // -1 bin safety: covers rounded-score ties
    }
}

// ---- K4: compact candidates (mkey>>8 >= T), LDS-staged, ONE global atomic per block
__global__ __launch_bounds__(256) void k_compact(const uint32_t* __restrict__ mkey,
                                                 uint32_t* __restrict__ scal,
                                                 uint64_t* __restrict__ cand) {
    __shared__ uint32_t cnt;
    __shared__ uint32_t gbase;
    __shared__ uint64_t stg[1024];
    int t = threadIdx.x;
    int lane = t & 63;
    if (t == 0) cnt = 0;
    __syncthreads();
    uint32_t T = scal[SC_T24];
    size_t base = (size_t)blockIdx.x * 4096;
    for (int it = 0; it < 16; ++it) {
        uint32_t row = (uint32_t)(base + it * 256 + t);
        uint32_t u = mkey[row];
        bool pass = (u >> 8) >= T;
        unsigned long long bal = __ballot(pass);
        if (bal) {
            uint32_t wbase = 0;
            if (lane == 0) wbase = atomicAdd(&cnt, (uint32_t)__popcll(bal));
            wbase = __shfl(wbase, 0);
            if (pass) {
                uint32_t pos = wbase + (uint32_t)__popcll(bal & ((1ull << lane) - 1ull));
                if (pos < 1024) stg[pos] = ((uint64_t)u << 32) | row;
            }
        }
    }
    __syncthreads();
    uint32_t n = cnt; if (n > 1024) n = 1024;
    if (t == 0 && n) gbase = atomicAdd(&scal[SC_CNT], n);
    __syncthreads();
    if (n) {
        uint32_t gb = gbase;
        for (uint32_t i = t; i < n; i += 256) {
            uint32_t pos = gb + i;
            if (pos < (uint32_t)CAND_MAX) cand[pos] = stg[i];
        }
    }
}

// ---- K5: rank-by-counting (replaces bitonic sort; ~2 barriers, 16 blocks).
//      All blocks build identical key tables; block b ranks candidates [b*256, b*256+256).
//      rank = #{key64 < mine}; key64 = (~sigmoid_bits)<<32 | idx  -> (score desc, idx asc).
__global__ __launch_bounds__(256) void k_rank(const uint64_t* __restrict__ cand,
                                              uint32_t* __restrict__ scal,
                                              const float* __restrict__ deltas,
                                              const float* __restrict__ locs,
                                              const int* __restrict__ stridep,
                                              const uint8_t* __restrict__ cls,
                                              float* __restrict__ out) {
    __shared__ uint64_t keys[CAND_MAX];
    __shared__ float red[4];
    int t = threadIdx.x;
    uint32_t M = scal[SC_CNT];
    if (M > (uint32_t)CAND_MAX) M = CAND_MAX;

    for (uint32_t i = t; i < M; i += 256) {
        uint64_t cd = cand[i];
        uint32_t mk = (uint32_t)(cd >> 32);
        uint32_t row = (uint32_t)cd & (N_ROWS - 1);
        float m = mono_inv(mk);
        float ef = (float)exp(-(double)m);          // ~correctly-rounded fp32 expf
        float s = 1.0f / (1.0f + ef);
        keys[i] = ((uint64_t)(~__float_as_uint(s)) << 32) | row;
    }
    __syncthreads();

    uint32_t c = blockIdx.x * 256 + t;
    uint32_t rank = 0;
    uint64_t my = 0;
    if (c < M) {
        my = keys[c];
        uint32_t j = 0;
        for (; j + 4 <= M; j += 4) {                // uniform-address LDS reads -> broadcast
            ulonglong2 a = *(const ulonglong2*)&keys[j];
            ulonglong2 b = *(const ulonglong2*)&keys[j + 2];
            rank += (a.x < my) + (a.y < my) + (b.x < my) + (b.y < my);
        }
        for (; j < M; ++j) rank += (keys[j] < my);
    }

    float mx = -3.4e38f;
    if (c < M && rank < (uint32_t)K_TOP) {
        uint32_t row = (uint32_t)my & (N_ROWS - 1);
        float s = __uint_as_float(~(uint32_t)(my >> 32));
        float stridef = (float)(*stridep);
        float4 dl = ((const float4*)deltas)[row];
        float2 lc = ((const float2*)locs)[row];
        float d0 = dl.x * stridef, d1 = dl.y * stridef, d2 = dl.z * stridef, d3 = dl.w * stridef;
        float b0 = lc.x - d0, b1 = lc.y - d1, b2 = lc.x + d2, b3 = lc.y + d3;
        float4 bx = { b0, b1, b2, b3 };
        *(float4*)&out[4 * rank] = bx;
        out[8000 + rank] = s;
        out[10000 + rank] = (float)cls[row];
        mx = fmaxf(fmaxf(b0, b1), fmaxf(b2, b3));
    }
    // block max of selected coords -> global mono-key atomicMax (16 atomics total)
    for (int o = 32; o > 0; o >>= 1) mx = fmaxf(mx, __shfl_down(mx, o));
    if ((t & 63) == 0) red[t >> 6] = mx;
    __syncthreads();
    if (t == 0) {
        float m2 = fmaxf(fmaxf(red[0], red[1]), fmaxf(red[2], red[3]));
        atomicMax((unsigned int*)&scal[SC_MAXK], mono_key(m2));
    }
}

// ---- K6: pairwise suppression mask (quirky IoU replicated exactly); class-offset boxes
//      computed on the fly from out[] + max-coord scalar. NO fences (kernel boundary = coherence).
__global__ __launch_bounds__(256) void k_mask(const float* __restrict__ out,
                                              const uint32_t* __restrict__ scal,
                                              uint64_t* __restrict__ mask,
                                              unsigned long long* __restrict__ grp) {
    int wave = (int)((blockIdx.x * 256 + threadIdx.x) >> 6);
    int lane = threadIdx.x & 63;
    int i = wave >> 5;
    int jb = wave & 31;
    int j = jb * 64 + lane;
    float off1 = mono_inv(scal[SC_MAXK]) + 1.0f;    // max_coord + 1
    float4 boxi = *(const float4*)&out[4 * i];
    float oi = out[10000 + i] * off1;
    bool sup = false;
    if (j < K_TOP && j > i) {
        float4 boxj = *(const float4*)&out[4 * j];
        float oj = out[10000 + j] * off1;
        float x1i = boxi.x + oi, y2i = boxi.y + oi, x2i = boxi.z + oi, y1i = boxi.w + oi;
        float x1j = boxj.x + oj, y2j = boxj.y + oj, x2j = boxj.z + oj, y1j = boxj.w + oj;
        float ai = (x2i - x1i) * (y2i - y1i);
        float aj = (x2j - x1j) * (y2j - y1j);
        float xx1 = fmaxf(x1i, x1j);
        float yy1 = fminf(y1i, y1j);
        float xx2 = fminf(x2i, x2j);
        float yy2 = fmaxf(y2i, y2j);
        float inter = fabsf(xx2 - xx1) * fabsf(yy2 - yy1);
        float iou = inter / ((ai + aj) - inter);
        sup = iou > 0.5f;
    }
    unsigned long long bits = __ballot(sup);
    if (lane == 0) {
        mask[(size_t)i * 32 + jb] = bits;
        if (bits) atomicOr(&grp[i >> 6], 1ull << (i & 63));
    }
}

// ---- K7: sequential NMS scan over nonzero-mask rows only; final active == keep
__global__ void k_scan(const uint64_t* __restrict__ mask,
                       const unsigned long long* __restrict__ grp,
                       float* __restrict__ out) {
    int lane = threadIdx.x;  // 64 threads; lane w<32 holds active word w
    uint64_t g = (lane < 32) ? grp[lane] : 0ull;
    uint64_t active = ~0ull;
    if (__ballot(g != 0ull)) {
        for (int gg = 0; gg < 32; ++gg) {
            uint64_t nz = __shfl(g, gg);
            while (nz) {
                int b = __ffsll((long long)nz) - 1;
                nz &= nz - 1;
                int i = gg * 64 + b;
                uint64_t aw = __shfl(active, gg);
                bool kept = (aw >> b) & 1ull;
                uint64_t m = (lane < 32) ? mask[(size_t)i * 32 + lane] : 0ull;
                if (kept) active &= ~m;
            }
        }
    }
    if (lane < 32) {
        int limit = K_TOP - lane * 64;               // 64 for lanes<31, 16 for lane 31
        int nvec = limit < 64 ? limit / 4 : 16;
        for (int v = 0; v < nvec; ++v) {
            float4 f;
            f.x = ((active >> (4 * v + 0)) & 1ull) ? 1.0f : 0.0f;
            f.y = ((active >> (4 * v + 1)) & 1ull) ? 1.0f : 0.0f;
            f.z = ((active >> (4 * v + 2)) & 1ull) ? 1.0f : 0.0f;
            f.w = ((active >> (4 * v + 3)) & 1ull) ? 1.0f : 0.0f;
            *(float4*)&out[12000 + lane * 64 + 4 * v] = f;
        }
    }
}

extern "C" void kernel_launch(void* const* d_in, const int* in_sizes, int n_in,
                              void* d_out, int out_size, void* d_ws, size_t ws_size,
                              hipStream_t stream) {
    const float* deltas = (const float*)d_in[0];
    const float* locs   = (const float*)d_in[1];
    const float* logits = (const float*)d_in[2];
    const int*   stridep = (const int*)d_in[3];
    float* out = (float*)d_out;
    char* ws = (char*)d_ws;

    uint32_t* mkey   = (uint32_t*)(ws + OFF_MKEY);
    uint8_t*  cls    = (uint8_t*)(ws + OFF_CLS);
    uint32_t* hist1  = (uint32_t*)(ws + OFF_HIST1);
    uint32_t* hist16 = (uint32_t*)(ws + OFF_HIST16);
    uint32_t* scal   = (uint32_t*)(ws + OFF_SCAL);
    unsigned long long* grp = (unsigned long long*)(ws + OFF_GRP);
    uint64_t* cand   = (uint64_t*)(ws + OFF_CAND);
    uint64_t* mask   = (uint64_t*)(ws + OFF_MASK);

    k_init<<<dim3(1), dim3(1024), 0, stream>>>(hist1);
    k_score<<<dim3(1024), dim3(256), 0, stream>>>(logits, mkey, cls, hist1, hist16);
    k_hist16<<<dim3(1024), dim3(256), 0, stream>>>(mkey, hist1, hist16, scal);
    k_find16<<<dim3(1), dim3(1024), 0, stream>>>(hist16, scal);
    k_compact<<<dim3(256), dim3(256), 0, stream>>>(mkey, scal, cand);
    k_rank<<<dim3(16), dim3(256), 0, stream>>>(cand, scal, deltas, locs, stridep, cls, out);
    k_mask<<<dim3((K_TOP * 32) / 4), dim3(256), 0, stream>>>(out, scal, mask, grp);
    k_scan<<<dim3(1), dim3(64), 0, stream>>>(mask, grp, out);
}

// Round 5
// 106.869 us; speedup vs baseline: 10.1710x; 1.1395x over previous
//
#include <hip/hip_runtime.h>
#include <stdint.h>
#include <math.h>

#pragma clang fp contract(off)

#define N_ROWS 1048576
#define N_CLS  20
#define K_TOP  2000
#define CAND_MAX 4096
#define H_COPIES 4

// scal slots (dwords)
#define SC_CNT  0
#define SC_MAXK 1
#define SC_DONE 2

// ws layout
static constexpr size_t OFF_MKEY  = 0;                             // u32[N]
static constexpr size_t OFF_CLS   = OFF_MKEY + 4ull * N_ROWS;      // u8[N]
static constexpr size_t OFF_HIST1 = OFF_CLS + (size_t)N_ROWS;      // u32[4*256] -- zero region start
static constexpr size_t OFF_HIST2 = OFF_HIST1 + 4096;              // u32[4*256]
static constexpr size_t OFF_SCAL  = OFF_HIST2 + 4096;              // u32[16]
static constexpr size_t OFF_GRP   = OFF_SCAL + 64;                 // u64[32]    -- zero region end
static constexpr size_t OFF_CAND  = OFF_GRP + 256;                 // u64[CAND_MAX]
static constexpr size_t OFF_MASK  = OFF_CAND + 8ull * CAND_MAX;    // u64[K_TOP*32]
static constexpr int ZERO_DWORDS = H_COPIES * 256 * 2 + 16 + 64;   // 2128

__device__ __forceinline__ uint32_t mono_key(float f) {
    uint32_t u = __float_as_uint(f);
    return u ^ ((u & 0x80000000u) ? 0xFFFFFFFFu : 0x80000000u);
}
__device__ __forceinline__ float mono_inv(uint32_t k) {
    uint32_t u = (k & 0x80000000u) ? (k ^ 0x80000000u) : ~k;
    return __uint_as_float(u);
}

// ---- D1: per-row max/argmax of logits (LDS-staged coalesced loads) -> mkey, cls.
//      Also zeroes hist1/hist2/scal/grp (first written in later dispatches -> no race).
__global__ __launch_bounds__(256) void k_score(const float* __restrict__ logits,
                                               uint32_t* __restrict__ mkey,
                                               uint8_t* __restrict__ cls,
                                               uint32_t* __restrict__ zreg) {
    __shared__ uint32_t stage[256 * 21];   // 256 rows x 20 words, padded to 21
    int t = threadIdx.x;
    if (t < 4) {
        int zi = blockIdx.x * 4 + t;
        if (zi < ZERO_DWORDS) zreg[zi] = 0;
    }
    int waddr[20];
#pragma unroll
    for (int q = 0; q < 5; ++q) {
#pragma unroll
        for (int e = 0; e < 4; ++e) {
            int w = (q * 256 + t) * 4 + e;
            int r = w / 20, c = w - r * 20;
            waddr[q * 4 + e] = r * 21 + c;
        }
    }
    size_t blockRowBase = (size_t)blockIdx.x * 1024;
    for (int g = 0; g < 4; ++g) {
        const float4* src = (const float4*)(logits + (blockRowBase + (size_t)g * 256) * N_CLS);
#pragma unroll
        for (int q = 0; q < 5; ++q) {
            float4 v = src[q * 256 + t];            // fully coalesced 16B/lane
            stage[waddr[q * 4 + 0]] = __float_as_uint(v.x);
            stage[waddr[q * 4 + 1]] = __float_as_uint(v.y);
            stage[waddr[q * 4 + 2]] = __float_as_uint(v.z);
            stage[waddr[q * 4 + 3]] = __float_as_uint(v.w);
        }
        __syncthreads();
        const uint32_t* row = &stage[t * 21];
        float m = __uint_as_float(row[0]); int ci = 0;
#pragma unroll
        for (int c = 1; c < 20; ++c) {
            float v = __uint_as_float(row[c]);
            if (v > m) { m = v; ci = c; }
        }
        size_t rowIdx = blockRowBase + (size_t)g * 256 + t;
        mkey[rowIdx] = mono_key(m);
        cls[rowIdx] = (uint8_t)ci;
        __syncthreads();
    }
}

// ---- D2: global 256-bin top-byte histogram (LDS pre-agg, 4 spread copies)
__global__ __launch_bounds__(256) void k_hist1(const uint32_t* __restrict__ mkey,
                                               uint32_t* __restrict__ hist1) {
    __shared__ uint32_t h[256];
    int t = threadIdx.x;
    h[t] = 0;
    __syncthreads();
    const uint4* m4 = (const uint4*)mkey;
    size_t base = (size_t)blockIdx.x * 1024;
    for (int it = 0; it < 4; ++it) {
        uint4 v = m4[base + it * 256 + t];
        atomicAdd(&h[v.x >> 24], 1u);
        atomicAdd(&h[v.y >> 24], 1u);
        atomicAdd(&h[v.z >> 24], 1u);
        atomicAdd(&h[v.w >> 24], 1u);
    }
    __syncthreads();
    uint32_t hv = h[t];
    if (hv) atomicAdd(&hist1[(blockIdx.x & (H_COPIES - 1)) * 256 + t], hv);
}

// find8: suffix scan over summed hist1 -> (b0, R1). Runs redundantly per block.
__device__ __forceinline__ void find8(const uint32_t* __restrict__ hist1,
                                      uint32_t* sfx, uint32_t* pb0, uint32_t* pR1,
                                      uint32_t& b0, uint32_t& R1) {
    int t = threadIdx.x;
    uint32_t h = 0;
#pragma unroll
    for (int k = 0; k < H_COPIES; ++k) h += hist1[k * 256 + t];
    sfx[t] = h;
    __syncthreads();
    for (int off = 1; off < 256; off <<= 1) {
        uint32_t v = (t + off < 256) ? sfx[t + off] : 0;
        __syncthreads();
        sfx[t] += v;
        __syncthreads();
    }
    if (sfx[t] >= (uint32_t)K_TOP && (t == 255 || sfx[t + 1] < (uint32_t)K_TOP)) {
        *pb0 = (uint32_t)t;
        *pR1 = (uint32_t)K_TOP - (sfx[t] - h);
    }
    __syncthreads();
    b0 = *pb0; R1 = *pR1;
}

// ---- D3: restricted 8-bit stage-2 histogram (bits 23:16 where top byte == b0)
__global__ __launch_bounds__(256) void k_hist2(const uint32_t* __restrict__ mkey,
                                               const uint32_t* __restrict__ hist1,
                                               uint32_t* __restrict__ hist2) {
    __shared__ uint32_t sfx[256];
    __shared__ uint32_t h2[256];
    __shared__ uint32_t sb0, sR1;
    int t = threadIdx.x;
    h2[t] = 0;
    uint32_t b0, R1;
    find8(hist1, sfx, &sb0, &sR1, b0, R1);
    uint4 v = ((const uint4*)mkey)[(size_t)blockIdx.x * 256 + t];  // 1024 rows/block
    if ((v.x >> 24) == b0) atomicAdd(&h2[(v.x >> 16) & 0xFFu], 1u);
    if ((v.y >> 24) == b0) atomicAdd(&h2[(v.y >> 16) & 0xFFu], 1u);
    if ((v.z >> 24) == b0) atomicAdd(&h2[(v.z >> 16) & 0xFFu], 1u);
    if ((v.w >> 24) == b0) atomicAdd(&h2[(v.w >> 16) & 0xFFu], 1u);
    __syncthreads();
    uint32_t hv = h2[t];
    if (hv) atomicAdd(&hist2[(blockIdx.x & (H_COPIES - 1)) * 256 + t], hv);
}

// ---- D4: per-block redundant final find (find8 + stage-2 suffix scan -> T16-1),
//      then compact candidates ((mkey>>16) >= T), LDS-staged, 1 global atomic/block.
__global__ __launch_bounds__(256) void k_compact(const uint32_t* __restrict__ mkey,
                                                 const uint32_t* __restrict__ hist1,
                                                 const uint32_t* __restrict__ hist2,
                                                 uint32_t* __restrict__ scal,
                                                 uint64_t* __restrict__ cand) {
    __shared__ uint32_t sfx[256];
    __shared__ uint32_t sb0, sR1, sT;
    __shared__ uint32_t cnt, gbase;
    __shared__ uint64_t stg[1024];
    int t = threadIdx.x;
    int lane = t & 63;
    if (t == 0) cnt = 0;
    uint32_t b0, R1;
    find8(hist1, sfx, &sb0, &sR1, b0, R1);
    // stage-2 suffix scan (reuse sfx)
    uint32_t h = 0;
#pragma unroll
    for (int k = 0; k < H_COPIES; ++k) h += hist2[k * 256 + t];
    __syncthreads();
    sfx[t] = h;
    __syncthreads();
    for (int off = 1; off < 256; off <<= 1) {
        uint32_t v = (t + off < 256) ? sfx[t + off] : 0;
        __syncthreads();
        sfx[t] += v;
        __syncthreads();
    }
    if (sfx[t] >= R1 && (t == 255 || sfx[t + 1] < R1)) {
        uint32_t t16 = (b0 << 8) | (uint32_t)t;
        sT = (t16 > 0) ? (t16 - 1) : 0;            // -1 bin safety: rounded-sigmoid ties
    }
    __syncthreads();
    uint32_t T = sT;
    const uint4* m4 = (const uint4*)mkey;
    size_t base = (size_t)blockIdx.x * 1024;       // uint4 index; 4096 rows/block
    for (int it = 0; it < 4; ++it) {
        uint32_t r0 = (uint32_t)((base + it * 256 + t) * 4);
        uint4 v = m4[base + it * 256 + t];
#pragma unroll
        for (int e = 0; e < 4; ++e) {
            uint32_t u = (e == 0) ? v.x : (e == 1) ? v.y : (e == 2) ? v.z : v.w;
            bool pass = (u >> 16) >= T;
            unsigned long long bal = __ballot(pass);
            if (bal) {
                uint32_t wbase = 0;
                if (lane == 0) wbase = atomicAdd(&cnt, (uint32_t)__popcll(bal));
                wbase = __shfl(wbase, 0);
                if (pass) {
                    uint32_t pos = wbase + (uint32_t)__popcll(bal & ((1ull << lane) - 1ull));
                    if (pos < 1024) stg[pos] = ((uint64_t)u << 32) | (r0 + e);
                }
            }
        }
    }
    __syncthreads();
    uint32_t n = cnt; if (n > 1024) n = 1024;
    if (t == 0 && n) gbase = atomicAdd(&scal[SC_CNT], n);
    __syncthreads();
    if (n) {
        uint32_t gb = gbase;
        for (uint32_t i = t; i < n; i += 256) {
            uint32_t pos = gb + i;
            if (pos < (uint32_t)CAND_MAX) cand[pos] = stg[i];
        }
    }
}

// ---- D5: rank-by-counting; decode boxes; write outputs; max-coord atomicMax.
__global__ __launch_bounds__(256) void k_rank(const uint64_t* __restrict__ cand,
                                              uint32_t* __restrict__ scal,
                                              const float* __restrict__ deltas,
                                              const float* __restrict__ locs,
                                              const int* __restrict__ stridep,
                                              const uint8_t* __restrict__ cls,
                                              float* __restrict__ out) {
    __shared__ uint64_t keys[CAND_MAX];
    __shared__ float red[4];
    int t = threadIdx.x;
    uint32_t M = scal[SC_CNT];
    if (M > (uint32_t)CAND_MAX) M = CAND_MAX;

    for (uint32_t i = t; i < M; i += 256) {
        uint64_t cd = cand[i];
        uint32_t mk = (uint32_t)(cd >> 32);
        uint32_t row = (uint32_t)cd & (N_ROWS - 1);
        float m = mono_inv(mk);
        float ef = (float)exp(-(double)m);          // ~correctly-rounded fp32 expf
        float s = 1.0f / (1.0f + ef);
        keys[i] = ((uint64_t)(~__float_as_uint(s)) << 32) | row;
    }
    __syncthreads();

    uint32_t c = blockIdx.x * 256 + t;
    uint32_t rank = 0;
    uint64_t my = 0;
    if (c < M) {
        my = keys[c];
        uint32_t j = 0;
        for (; j + 4 <= M; j += 4) {                // uniform-address LDS reads -> broadcast
            ulonglong2 a = *(const ulonglong2*)&keys[j];
            ulonglong2 b = *(const ulonglong2*)&keys[j + 2];
            rank += (a.x < my) + (a.y < my) + (b.x < my) + (b.y < my);
        }
        for (; j < M; ++j) rank += (keys[j] < my);
    }

    float mx = -3.4e38f;
    if (c < M && rank < (uint32_t)K_TOP) {
        uint32_t row = (uint32_t)my & (N_ROWS - 1);
        float s = __uint_as_float(~(uint32_t)(my >> 32));
        float stridef = (float)(*stridep);
        float4 dl = ((const float4*)deltas)[row];
        float2 lc = ((const float2*)locs)[row];
        float d0 = dl.x * stridef, d1 = dl.y * stridef, d2 = dl.z * stridef, d3 = dl.w * stridef;
        float b0 = lc.x - d0, b1 = lc.y - d1, b2 = lc.x + d2, b3 = lc.y + d3;
        float4 bx = { b0, b1, b2, b3 };
        *(float4*)&out[4 * rank] = bx;
        out[8000 + rank] = s;
        out[10000 + rank] = (float)cls[row];
        mx = fmaxf(fmaxf(b0, b1), fmaxf(b2, b3));
    }
    for (int o = 32; o > 0; o >>= 1) mx = fmaxf(mx, __shfl_down(mx, o));
    if ((t & 63) == 0) red[t >> 6] = mx;
    __syncthreads();
    if (t == 0) {
        float m2 = fmaxf(fmaxf(red[0], red[1]), fmaxf(red[2], red[3]));
        atomicMax((unsigned int*)&scal[SC_MAXK], mono_key(m2));
    }
}

// ---- D6: pairwise suppression mask (quirky IoU replicated exactly) + fused scan.
//      Atomic-only cross-block handoff: atomicExch payload (device-coherent, overwrites
//      poison), consume returns + s_waitcnt (cheap wave drain, NOT a cache flush),
//      done-counter; last block scans via atomic fetches. 500 blocks, wave = one i-row.
__global__ __launch_bounds__(256) void k_maskscan(const float* __restrict__ out_ro,
                                                  uint32_t* __restrict__ scal,
                                                  uint64_t* __restrict__ mask,
                                                  unsigned long long* __restrict__ grp,
                                                  float* __restrict__ out) {
    __shared__ int lastdone;
    int t = threadIdx.x;
    int lane = t & 63;
    int i = blockIdx.x * 4 + (t >> 6);              // 2000 waves total
    float off1 = mono_inv(scal[SC_MAXK]) + 1.0f;    // max_coord + 1 (prev dispatch, coherent)
    float4 boxi = *(const float4*)&out_ro[4 * i];
    float oi = out_ro[10000 + i] * off1;
    float x1i = boxi.x + oi, y2i = boxi.y + oi, x2i = boxi.z + oi, y1i = boxi.w + oi;
    float ai = (x2i - x1i) * (y2i - y1i);
    unsigned long long dummy = 0;
    for (int jb = 0; jb < 32; ++jb) {
        int j = jb * 64 + lane;
        bool sup = false;
        if (j < K_TOP && j > i) {
            float4 boxj = *(const float4*)&out_ro[4 * j];
            float oj = out_ro[10000 + j] * off1;
            float x1j = boxj.x + oj, y2j = boxj.y + oj, x2j = boxj.z + oj, y1j = boxj.w + oj;
            float aj = (x2j - x1j) * (y2j - y1j);
            float xx1 = fmaxf(x1i, x1j);
            float yy1 = fminf(y1i, y1j);
            float xx2 = fminf(x2i, x2j);
            float yy2 = fmaxf(y2i, y2j);
            float inter = fabsf(xx2 - xx1) * fabsf(yy2 - yy1);
            float iou = inter / ((ai + aj) - inter);
            sup = iou > 0.5f;
        }
        unsigned long long bits = __ballot(sup);
        if (lane == 0) {
            dummy += atomicExch(&mask[(size_t)i * 32 + jb], bits);
            if (bits) dummy += atomicOr(&grp[i >> 6], 1ull << (i & 63));
        }
    }
    asm volatile("" :: "v"(dummy));                 // force atomic returns (vmcnt drained)
    asm volatile("s_waitcnt vmcnt(0) lgkmcnt(0)" ::: "memory");
    __syncthreads();
    if (t == 0) {
        unsigned old = atomicAdd(&scal[SC_DONE], 1u);
        lastdone = (old == (unsigned)(gridDim.x - 1)) ? 1 : 0;
    }
    __syncthreads();
    if (!lastdone) return;

    if (t < 64) {
        int l = t;                                  // lane w<32 holds active word w
        uint64_t g = (l < 32) ? atomicOr(&grp[l], 0ull) : 0ull;
        uint64_t active = ~0ull;
        if (__ballot(g != 0ull)) {
            for (int gg = 0; gg < 32; ++gg) {
                uint64_t nz = __shfl(g, gg);
                while (nz) {
                    int b = __ffsll((long long)nz) - 1;
                    nz &= nz - 1;
                    int ii = gg * 64 + b;
                    uint64_t aw = __shfl(active, gg);
                    bool kept = (aw >> b) & 1ull;
                    uint64_t m = (l < 32) ? atomicOr(&mask[(size_t)ii * 32 + l], 0ull) : 0ull;
                    if (kept) active &= ~m;
                }
            }
        }
        if (l < 32) {
            int limit = K_TOP - l * 64;
            int nvec = limit < 64 ? limit / 4 : 16;
            for (int v = 0; v < nvec; ++v) {
                float4 f;
                f.x = ((active >> (4 * v + 0)) & 1ull) ? 1.0f : 0.0f;
                f.y = ((active >> (4 * v + 1)) & 1ull) ? 1.0f : 0.0f;
                f.z = ((active >> (4 * v + 2)) & 1ull) ? 1.0f : 0.0f;
                f.w = ((active >> (4 * v + 3)) & 1ull) ? 1.0f : 0.0f;
                *(float4*)&out[12000 + l * 64 + 4 * v] = f;
            }
        }
    }
}

extern "C" void kernel_launch(void* const* d_in, const int* in_sizes, int n_in,
                              void* d_out, int out_size, void* d_ws, size_t ws_size,
                              hipStream_t stream) {
    const float* deltas = (const float*)d_in[0];
    const float* locs   = (const float*)d_in[1];
    const float* logits = (const float*)d_in[2];
    const int*   stridep = (const int*)d_in[3];
    float* out = (float*)d_out;
    char* ws = (char*)d_ws;

    uint32_t* mkey  = (uint32_t*)(ws + OFF_MKEY);
    uint8_t*  cls   = (uint8_t*)(ws + OFF_CLS);
    uint32_t* hist1 = (uint32_t*)(ws + OFF_HIST1);
    uint32_t* hist2 = (uint32_t*)(ws + OFF_HIST2);
    uint32_t* scal  = (uint32_t*)(ws + OFF_SCAL);
    unsigned long long* grp = (unsigned long long*)(ws + OFF_GRP);
    uint64_t* cand  = (uint64_t*)(ws + OFF_CAND);
    uint64_t* mask  = (uint64_t*)(ws + OFF_MASK);

    k_score<<<dim3(1024), dim3(256), 0, stream>>>(logits, mkey, cls, hist1);
    k_hist1<<<dim3(256), dim3(256), 0, stream>>>(mkey, hist1);
    k_hist2<<<dim3(1024), dim3(256), 0, stream>>>(mkey, hist1, hist2);
    k_compact<<<dim3(256), dim3(256), 0, stream>>>(mkey, hist1, hist2, scal, cand);
    k_rank<<<dim3(16), dim3(256), 0, stream>>>(cand, scal, deltas, locs, stridep, cls, out);
    k_maskscan<<<dim3(500), dim3(256), 0, stream>>>(out, scal, mask, grp, out);
}